// Round 6
// baseline (279.560 us; speedup 1.0000x reference)
//
#include <hip/hip_runtime.h>

// PMField R13: 64 particles/wave (Nt=4) — amortize overhead, ILP not occupancy.
//  - R8..R12: dur pinned 181-194us across LDS 4-48KB, VGPR 84-256, 1/2/4-wave
//    blocks; occupancy 11-26% with ZERO duration response. Machine settles at
//    ~2 waves/SIMD regardless. Bottom-up floor ~50us vs 190 actual => per-wave
//    issue overhead + dep-chain stalls dominate, not residency.
//  - Fix: each wave owns 64 particles (4 Nt column-groups of 16):
//      * frag loads (wsA/wsG/cn/mu) + all addressing serve 2x particles
//      * 4 independent Nt chains fill MFMA/VALU latency within the wave
//      * L2 frag traffic halves (2.1 -> 1.05 GB)
//  - Geometry: 128-thr blocks (2 waves) x 128 particles = grid 1024 = 4
//    blocks/CU (under the ~8 workgroup-slot cap seen in R11). LDS 32KB/block:
//    per wave 8 z-planes + 8 w-planes (1KB each, separate, no reuse hazard).
//    zf frags re-read per chunk from z-planes to bound reg peak (~220).
//  - __launch_bounds__(128,2) -> VGPR cap 256 (R8-proven safe; only caps
//    <=128 ever triggered the spill heuristic). Spill tripwire: WRITE_SIZE.
//  - Keeps: acc-init fold (zz+cn2 in MFMA acc init, r2=fmax(S,EPS)), f32
//    cn2/mu float4 loads, v_perm packs, unroll 1 on chunk loop, no barriers.
// Layouts (HW-verified): C/D col=lane&15,row=q*4+r; A[m=lane&15][k=q*8+j];
// B = transpose-dual of A. Scatter: dim d=16Mt+4q+r -> plane Kt=Mt>>1,
// lane m16+16*((2Mt+(q>>1))&3), uint 2(q&1)+(r>>1).

#define STEPS 8
#define DTB   0.15f
#define EPSF  1e-4f

typedef short bf16x8 __attribute__((ext_vector_type(8)));
typedef float f32x4  __attribute__((ext_vector_type(4)));
union FragU { int4 i; bf16x8 h; };

// byte-select pack: r = [lo.b2, lo.b3, hi.b2, hi.b3]  (one v_perm_b32)
__device__ __forceinline__ unsigned bfpt(float lo, float hi) { // trunc pack
    return __builtin_amdgcn_perm(__float_as_uint(hi), __float_as_uint(lo),
                                 0x07060302u);
}
__device__ __forceinline__ unsigned bfp(float lo, float hi) {  // round pack
    return __builtin_amdgcn_perm(__float_as_uint(hi) + 0x8000u,
                                 __float_as_uint(lo) + 0x8000u, 0x07060302u);
}
__device__ __forceinline__ float med3(float x, float lo, float hi) {
    return __builtin_amdgcn_fmed3f(x, lo, hi);
}

// d_ws layout:
//   int4 [0,    2048)  S-planes: ((c*4+Mt)*2+h)*64 + lane = bf16x8 of -2C[center][dims]
//   int4 [2048, 4096)  G-planes: ((Mt*4+c)*2+h)*64 + lane = bf16x8 of C^T[dim][centers]
//   f32  ws[16384..16640)  cn2[256]   (|c|^2, full precision)
//   f32  ws[16640..16896)  mu[256]
__global__ void pm_prep(const float* __restrict__ centers,
                        const float* __restrict__ mus,
                        unsigned* __restrict__ ws) {
    const int gtid = blockIdx.x * 256 + threadIdx.x;
    if (gtid < 2048) {                       // S-plane frags
        const int c = gtid >> 9, Mt = (gtid >> 7) & 3, h = (gtid >> 6) & 1;
        const int L = gtid & 63, m16 = L & 15, q = L >> 4;
        const float* row = centers + (size_t)(64 * c + 16 * Mt + m16) * 64 + 32 * h + 8 * q;
        uint4 u;
        u.x = bfp(-2.f * row[0], -2.f * row[1]);
        u.y = bfp(-2.f * row[2], -2.f * row[3]);
        u.z = bfp(-2.f * row[4], -2.f * row[5]);
        u.w = bfp(-2.f * row[6], -2.f * row[7]);
        ((uint4*)ws)[gtid] = u;
    } else if (gtid < 4096) {                // G-plane frags (C^T)
        const int i = gtid - 2048;
        const int Mt = i >> 9, c = (i >> 7) & 3, h = (i >> 6) & 1;
        const int L = i & 63, m16 = L & 15, q = L >> 4;
        const float* base = centers + (size_t)(64 * c + 32 * h + 8 * q) * 64 + 16 * Mt + m16;
        uint4 u;
        u.x = bfp(base[0],   base[64]);
        u.y = bfp(base[128], base[192]);
        u.z = bfp(base[256], base[320]);
        u.w = bfp(base[384], base[448]);
        ((uint4*)ws)[gtid] = u;
    } else if (gtid < 4352) {                // cn2 / mu as f32
        const int t = gtid - 4096;
        const float* r = centers + (size_t)t * 64;
        float a0 = 0.f, a1 = 0.f, a2 = 0.f, a3 = 0.f;
#pragma unroll
        for (int d = 0; d < 64; d += 4) {
            a0 = fmaf(r[d],     r[d],     a0);
            a1 = fmaf(r[d + 1], r[d + 1], a1);
            a2 = fmaf(r[d + 2], r[d + 2], a2);
            a3 = fmaf(r[d + 3], r[d + 3], a3);
        }
        float c2 = (a0 + a1) + (a2 + a3);
        ((float*)ws)[16384 + t] = c2;
        ((float*)ws)[16640 + t] = mus[t];
    }
}

__global__ __launch_bounds__(128, 2)
void pm_main(const float* __restrict__ z_in,
             const unsigned* __restrict__ ws,
             float* __restrict__ z_out) {
    __shared__ int4 sZ[2][8][64];      // 16 KB: per-wave z B-frag planes (Kt*4+Nt)
    __shared__ int4 sW[2][8][64];      // 16 KB: per-wave w B-frag planes

    const int4* wsA = (const int4*)ws;        // S-plane frags (L2-resident)
    const int4* wsG = wsA + 2048;             // G-plane frags (L2-resident)
    const float* wsC  = (const float*)ws + 16384;
    const float* wsMu = (const float*)ws + 16640;

    const int tid  = threadIdx.x;
    const int lane = tid & 63;
    const int w    = tid >> 6;         // wave 0/1
    const int m16  = lane & 15;
    const int q    = lane >> 4;

    const int pbase = blockIdx.x * 128 + w * 64;   // this wave's 64 particles

    // z state in C/D layout: lane holds dims {16Mt+4q..+3} x particles {m16+16Nt}
    f32x4 z[4][4];
#pragma unroll
    for (int Mt = 0; Mt < 4; ++Mt)
#pragma unroll
        for (int Nt = 0; Nt < 4; ++Nt)
            z[Mt][Nt] = *(const f32x4*)(z_in + (size_t)(pbase + m16 + 16 * Nt) * 64
                                        + 16 * Mt + 4 * q);

    unsigned* zp = (unsigned*)&sZ[w][0][0];   // 2048 uints, wave-private
    unsigned* wp = (unsigned*)&sW[w][0][0];

#pragma unroll 1
    for (int s = 0; s < STEPS; ++s) {
        // zz per particle (butterfly over q groups)
        float zzp[4];
#pragma unroll
        for (int Nt = 0; Nt < 4; ++Nt) {
            float a = 0.f;
#pragma unroll
            for (int Mt = 0; Mt < 4; ++Mt)
#pragma unroll
                for (int r = 0; r < 4; ++r) a = fmaf(z[Mt][Nt][r], z[Mt][Nt][r], a);
            a += __shfl_xor(a, 16, 64);
            a += __shfl_xor(a, 32, 64);
            zzp[Nt] = a;
        }

        // z (C/D regs) -> z B-frag planes: scatter write (wave-internal, in-order)
#pragma unroll
        for (int Mt = 0; Mt < 4; ++Mt) {
            const int Kt = Mt >> 1;
            const int qt = (2 * Mt + (q >> 1)) & 3;
#pragma unroll
            for (int Nt = 0; Nt < 4; ++Nt) {
                const int pos = ((Kt * 4 + Nt) * 64 + m16 + 16 * qt) * 4 + 2 * (q & 1);
                *(uint2*)(zp + pos) = make_uint2(bfp(z[Mt][Nt][0], z[Mt][Nt][1]),
                                                 bfp(z[Mt][Nt][2], z[Mt][Nt][3]));
            }
        }

        f32x4 g[4][4];
#pragma unroll
        for (int Mt = 0; Mt < 4; ++Mt)
#pragma unroll
            for (int Nt = 0; Nt < 4; ++Nt) g[Mt][Nt] = (f32x4){0.f, 0.f, 0.f, 0.f};
        float nacc[4] = {0.f, 0.f, 0.f, 0.f}, swp[4] = {0.f, 0.f, 0.f, 0.f};

#pragma unroll 1
        for (int c = 0; c < 4; ++c) {          // 4 chunks x 64 centers
            // z frags for this chunk (lane-linear, conflict-free b128)
            FragU zf[2][4];
#pragma unroll
            for (int Kt = 0; Kt < 2; ++Kt)
#pragma unroll
                for (int Nt = 0; Nt < 4; ++Nt)
                    zf[Kt][Nt].i = sZ[w][Kt * 4 + Nt][lane];

            // S-phase, fused per Mt; acc INIT carries zz + cn2 (C/D row match)
#pragma unroll
            for (int Mt = 0; Mt < 4; ++Mt) {
                FragU a0, a1;
                a0.i = wsA[((c * 4 + Mt) * 2 + 0) * 64 + lane];   // L2-resident
                a1.i = wsA[((c * 4 + Mt) * 2 + 1) * 64 + lane];
                const float4 cn4 = *(const float4*)(wsC  + 64 * c + 16 * Mt + 4 * q);
                const float4 mu4 = *(const float4*)(wsMu + 64 * c + 16 * Mt + 4 * q);
                f32x4 S[4];
#pragma unroll
                for (int Nt = 0; Nt < 4; ++Nt) {
                    f32x4 acc;
                    acc[0] = zzp[Nt] + cn4.x;
                    acc[1] = zzp[Nt] + cn4.y;
                    acc[2] = zzp[Nt] + cn4.z;
                    acc[3] = zzp[Nt] + cn4.w;
                    acc = __builtin_amdgcn_mfma_f32_16x16x32_bf16(a0.h, zf[0][Nt].h, acc, 0, 0, 0);
                    acc = __builtin_amdgcn_mfma_f32_16x16x32_bf16(a1.h, zf[1][Nt].h, acc, 0, 0, 0);
                    S[Nt] = acc;   // S = zz + |c|^2 - 2 z.c; row = center 64c+16Mt+4q+r
                }

                float wv[4][4];
#pragma unroll
                for (int r = 0; r < 4; ++r) {
                    const float mu = (r == 0) ? mu4.x : (r == 1) ? mu4.y
                                   : (r == 2) ? mu4.z : mu4.w;
#pragma unroll
                    for (int Nt = 0; Nt < 4; ++Nt) {
                        float r2  = fmaxf(S[Nt][r], EPSF);      // == max(.,0)+eps here
                        float rin = __builtin_amdgcn_rsqf(r2);
                        float mur = mu * rin;
                        nacc[Nt] += mur;
                        float wval = mur * rin * rin;           // mu / r^3
                        swp[Nt] += wval;
                        wv[Nt][r] = wval;
                    }
                }
                const int Kt = Mt >> 1;
                const int qt = (2 * Mt + (q >> 1)) & 3;
#pragma unroll
                for (int Nt = 0; Nt < 4; ++Nt) {
                    const int pos = ((Kt * 4 + Nt) * 64 + m16 + 16 * qt) * 4 + 2 * (q & 1);
                    *(uint2*)(wp + pos) = make_uint2(bfpt(wv[Nt][0], wv[Nt][1]),
                                                     bfpt(wv[Nt][2], wv[Nt][3]));
                }
            }

            // G-phase: wf frags (lane-linear LDS) + global ga frags (L2)
            FragU wf[2][4];
#pragma unroll
            for (int Kt = 0; Kt < 2; ++Kt)
#pragma unroll
                for (int Nt = 0; Nt < 4; ++Nt)
                    wf[Kt][Nt].i = sW[w][Kt * 4 + Nt][lane];
#pragma unroll
            for (int Mt = 0; Mt < 4; ++Mt) {
                FragU ga0, ga1;
                ga0.i = wsG[((Mt * 4 + c) * 2 + 0) * 64 + lane];
                ga1.i = wsG[((Mt * 4 + c) * 2 + 1) * 64 + lane];
#pragma unroll
                for (int Nt = 0; Nt < 4; ++Nt) {
                    g[Mt][Nt] = __builtin_amdgcn_mfma_f32_16x16x32_bf16(ga0.h, wf[0][Nt].h, g[Mt][Nt], 0, 0, 0);
                    g[Mt][Nt] = __builtin_amdgcn_mfma_f32_16x16x32_bf16(ga1.h, wf[1][Nt].h, g[Mt][Nt], 0, 0, 0);
                }
            }
        }

        // reduce n, sw across q groups; update z
        float tco[4], swf[4];
#pragma unroll
        for (int Nt = 0; Nt < 4; ++Nt) {
            float a = nacc[Nt];
            a += __shfl_xor(a, 16, 64);
            a += __shfl_xor(a, 32, 64);
            float b = swp[Nt];
            b += __shfl_xor(b, 16, 64);
            b += __shfl_xor(b, 32, 64);
            tco[Nt] = DTB * __builtin_amdgcn_rcpf(1.f + a);
            swf[Nt] = b;
        }
#pragma unroll
        for (int Mt = 0; Mt < 4; ++Mt)
#pragma unroll
            for (int Nt = 0; Nt < 4; ++Nt)
#pragma unroll
                for (int r = 0; r < 4; ++r) {
                    float gd = fmaf(-swf[Nt], z[Mt][Nt][r], g[Mt][Nt][r]);
                    z[Mt][Nt][r] = med3(fmaf(tco[Nt], gd, z[Mt][Nt][r]), -3.f, 3.f);
                }
    }

    // direct C/D-layout store (16B segments, rows covered across lanes)
#pragma unroll
    for (int Mt = 0; Mt < 4; ++Mt)
#pragma unroll
        for (int Nt = 0; Nt < 4; ++Nt)
            *(f32x4*)(z_out + (size_t)(pbase + m16 + 16 * Nt) * 64
                      + 16 * Mt + 4 * q) = z[Mt][Nt];
}

extern "C" void kernel_launch(void* const* d_in, const int* in_sizes, int n_in,
                              void* d_out, int out_size, void* d_ws, size_t ws_size,
                              hipStream_t stream) {
    const float* z       = (const float*)d_in[0];
    const float* centers = (const float*)d_in[1];
    const float* mus     = (const float*)d_in[2];
    float* out           = (float*)d_out;
    unsigned* ws         = (unsigned*)d_ws;

    pm_prep<<<dim3(17), dim3(256), 0, stream>>>(centers, mus, ws);
    // 131072 particles / (2 waves x 64) = 1024 blocks = 4 blocks/CU,
    // LDS 32KB -> 4-resident, 8 waves/CU (the empirically achievable level),
    // each wave with 2x work and 4 independent Nt chains
    pm_main<<<dim3(1024), dim3(128), 0, stream>>>(z, ws, out);
}

// Round 7
// 211.836 us; speedup vs baseline: 1.3197x; 1.3197x over previous
//
#include <hip/hip_runtime.h>

// PMField R14: packed-f32 (VOP3P) math on the R8 skeleton.
//  - R13 post-mortem: Nt=4 body needs ~290 VGPR; (128,2)'s 256 budget clamped
//    to 128 + scratch (WRITE 362MB) -> void. Register file can't hold 64
//    particles/wave of state.
//  - R7-R13 meta: dur pinned 181-194us across ALL residency knobs (LDS 4-48KB,
//    VGPR 84-256, 1/2/4-wave blocks, occ 11-26%). Not occupancy/HBM/MFMA/LDS
//    bound. VALU is the busiest pipe (55-61%); implied VALU-issue time ~100us
//    per SIMD ~= most of the wall. => cut VALU instruction COUNT.
//  - This round: f32x2 packed math (v_pk_add/mul/fma/max_f32) through the
//    elementwise core (24 scalar VALU + 4 rsq -> 12 pk + 4 rsq per (Mt,Nt)),
//    acc-init, zz, and z-update (pk_fma + pk_max/min clamp). Identical
//    numerics (same op dag, contraction already on).
//  - Geometry: EXACT R8 (best: 181.9us): 256 thr, sA 32KB staged + sWF 16KB,
//    (256,2) (the proven no-spill point), grid 1024, frags G/cn/mu from L2.
// Layouts (HW-verified): C/D col=lane&15,row=q*4+r; A[m=lane&15][k=q*8+j];
// B = transpose-dual of A.

#define STEPS 8
#define DTB   0.15f
#define EPSF  1e-4f

typedef short bf16x8 __attribute__((ext_vector_type(8)));
typedef float f32x4  __attribute__((ext_vector_type(4)));
typedef float f32x2  __attribute__((ext_vector_type(2)));
union FragU { int4 i; bf16x8 h; };

__device__ __forceinline__ f32x2 max2(f32x2 a, f32x2 b) {
    return __builtin_elementwise_max(a, b);
}
__device__ __forceinline__ f32x2 min2(f32x2 a, f32x2 b) {
    return __builtin_elementwise_min(a, b);
}

// byte-select pack: r = [lo.b2, lo.b3, hi.b2, hi.b3]  (one v_perm_b32)
__device__ __forceinline__ unsigned bfpt(float lo, float hi) { // trunc pack
    return __builtin_amdgcn_perm(__float_as_uint(hi), __float_as_uint(lo),
                                 0x07060302u);
}
__device__ __forceinline__ unsigned bfp(float lo, float hi) {  // round pack
    return __builtin_amdgcn_perm(__float_as_uint(hi) + 0x8000u,
                                 __float_as_uint(lo) + 0x8000u, 0x07060302u);
}

// d_ws layout:
//   int4 [0,    2048)  S-planes: ((c*4+Mt)*2+h)*64 + lane = bf16x8 of -2C[center][dims]
//   int4 [2048, 4096)  G-planes: ((Mt*4+c)*2+h)*64 + lane = bf16x8 of C^T[dim][centers]
//   f32  ws[16384..16640)  cn2[256]   (|c|^2, full precision)
//   f32  ws[16640..16896)  mu[256]
__global__ void pm_prep(const float* __restrict__ centers,
                        const float* __restrict__ mus,
                        unsigned* __restrict__ ws) {
    const int gtid = blockIdx.x * 256 + threadIdx.x;
    if (gtid < 2048) {                       // S-plane frags
        const int c = gtid >> 9, Mt = (gtid >> 7) & 3, h = (gtid >> 6) & 1;
        const int L = gtid & 63, m16 = L & 15, q = L >> 4;
        const float* row = centers + (size_t)(64 * c + 16 * Mt + m16) * 64 + 32 * h + 8 * q;
        uint4 u;
        u.x = bfp(-2.f * row[0], -2.f * row[1]);
        u.y = bfp(-2.f * row[2], -2.f * row[3]);
        u.z = bfp(-2.f * row[4], -2.f * row[5]);
        u.w = bfp(-2.f * row[6], -2.f * row[7]);
        ((uint4*)ws)[gtid] = u;
    } else if (gtid < 4096) {                // G-plane frags (C^T)
        const int i = gtid - 2048;
        const int Mt = i >> 9, c = (i >> 7) & 3, h = (i >> 6) & 1;
        const int L = i & 63, m16 = L & 15, q = L >> 4;
        const float* base = centers + (size_t)(64 * c + 32 * h + 8 * q) * 64 + 16 * Mt + m16;
        uint4 u;
        u.x = bfp(base[0],   base[64]);
        u.y = bfp(base[128], base[192]);
        u.z = bfp(base[256], base[320]);
        u.w = bfp(base[384], base[448]);
        ((uint4*)ws)[gtid] = u;
    } else if (gtid < 4352) {                // cn2 / mu as f32
        const int t = gtid - 4096;
        const float* r = centers + (size_t)t * 64;
        float a0 = 0.f, a1 = 0.f, a2 = 0.f, a3 = 0.f;
#pragma unroll
        for (int d = 0; d < 64; d += 4) {
            a0 = fmaf(r[d],     r[d],     a0);
            a1 = fmaf(r[d + 1], r[d + 1], a1);
            a2 = fmaf(r[d + 2], r[d + 2], a2);
            a3 = fmaf(r[d + 3], r[d + 3], a3);
        }
        float c2 = (a0 + a1) + (a2 + a3);
        ((float*)ws)[16384 + t] = c2;
        ((float*)ws)[16640 + t] = mus[t];
    }
}

__global__ __launch_bounds__(256, 2)
void pm_main(const float* __restrict__ z_in,
             const unsigned* __restrict__ ws,
             float* __restrict__ z_out) {
    __shared__ int4 sA[2048];          // 32 KB: S-plane frags, block-shared
    __shared__ int4 sWF[4][4][64];     // 16 KB: wave-private B-frag planes

    const int4* wsA = (const int4*)ws;
    const int4* wsG = wsA + 2048;             // G-plane frags (L2-resident)
    const float* wsC  = (const float*)ws + 16384;
    const float* wsMu = (const float*)ws + 16640;

    const int tid  = threadIdx.x;
    const int lane = tid & 63;
    const int w    = tid >> 6;
    const int m16  = lane & 15;
    const int q    = lane >> 4;

    // copy S planes to LDS (lane-linear, coalesced, conflict-free)
#pragma unroll
    for (int i = 0; i < 8; ++i) sA[i * 256 + tid] = wsA[i * 256 + tid];
    __syncthreads();

    const int pbase = blockIdx.x * 128;   // 128 particles/block, 32/wave

    // z state in C/D layout: lane holds dims {16Mt+4q..+3} x particles {m16, m16+16}
    f32x4 z[4][2];
#pragma unroll
    for (int Mt = 0; Mt < 4; ++Mt)
#pragma unroll
        for (int Nt = 0; Nt < 2; ++Nt)
            z[Mt][Nt] = *(const f32x4*)(z_in + (size_t)(pbase + 32 * w + m16 + 16 * Nt) * 64
                                        + 16 * Mt + 4 * q);

    unsigned* wp = (unsigned*)&sWF[w][0][0];   // wave-private, 1024 uints

#pragma unroll 1
    for (int s = 0; s < STEPS; ++s) {
        // zz per particle (pk pairs + butterfly over q groups)
        float zzp[2];
#pragma unroll
        for (int Nt = 0; Nt < 2; ++Nt) {
            f32x2 a2 = (f32x2){0.f, 0.f};
#pragma unroll
            for (int Mt = 0; Mt < 4; ++Mt) {
                f32x2 lo = (f32x2){z[Mt][Nt][0], z[Mt][Nt][1]};
                f32x2 hi = (f32x2){z[Mt][Nt][2], z[Mt][Nt][3]};
                a2 += lo * lo;
                a2 += hi * hi;
            }
            float a = a2.x + a2.y;
            a += __shfl_xor(a, 16, 64);
            a += __shfl_xor(a, 32, 64);
            zzp[Nt] = a;
        }

        // z (C/D regs) -> B-frag planes: scatter write (wave-internal, in-order)
#pragma unroll
        for (int Mt = 0; Mt < 4; ++Mt) {
            const int Kt = Mt >> 1;
            const int qt = (2 * Mt + (q >> 1)) & 3;
#pragma unroll
            for (int Nt = 0; Nt < 2; ++Nt) {
                const int pos = ((Kt * 2 + Nt) * 64 + m16 + 16 * qt) * 4 + 2 * (q & 1);
                *(uint2*)(wp + pos) = make_uint2(bfp(z[Mt][Nt][0], z[Mt][Nt][1]),
                                                 bfp(z[Mt][Nt][2], z[Mt][Nt][3]));
            }
        }
        FragU zf[2][2];
#pragma unroll
        for (int Kt = 0; Kt < 2; ++Kt)
#pragma unroll
            for (int Nt = 0; Nt < 2; ++Nt)
                zf[Kt][Nt].i = sWF[w][Kt * 2 + Nt][lane];   // lane-linear read

        f32x4 g[4][2];
#pragma unroll
        for (int Mt = 0; Mt < 4; ++Mt)
#pragma unroll
            for (int Nt = 0; Nt < 2; ++Nt) g[Mt][Nt] = (f32x4){0.f, 0.f, 0.f, 0.f};
        f32x2 nacc2[2] = {(f32x2){0.f, 0.f}, (f32x2){0.f, 0.f}};
        f32x2 swp2[2]  = {(f32x2){0.f, 0.f}, (f32x2){0.f, 0.f}};

#pragma unroll 1
        for (int c = 0; c < 4; ++c) {          // 4 chunks x 64 centers
            // S-phase, fused per Mt; acc INIT carries zz + cn2 (C/D row match)
#pragma unroll
            for (int Mt = 0; Mt < 4; ++Mt) {
                FragU a0, a1;
                a0.i = sA[((c * 4 + Mt) * 2 + 0) * 64 + lane];
                a1.i = sA[((c * 4 + Mt) * 2 + 1) * 64 + lane];
                const float4 cn4 = *(const float4*)(wsC  + 64 * c + 16 * Mt + 4 * q);
                const float4 mu4 = *(const float4*)(wsMu + 64 * c + 16 * Mt + 4 * q);
                const f32x2 cnlo = (f32x2){cn4.x, cn4.y}, cnhi = (f32x2){cn4.z, cn4.w};
                const f32x2 mulo = (f32x2){mu4.x, mu4.y}, muhi = (f32x2){mu4.z, mu4.w};
                f32x4 S[2];
#pragma unroll
                for (int Nt = 0; Nt < 2; ++Nt) {
                    const f32x2 zz2 = (f32x2){zzp[Nt], zzp[Nt]};
                    const f32x2 i0 = zz2 + cnlo, i1 = zz2 + cnhi;   // pk_add
                    f32x4 acc = (f32x4){i0.x, i0.y, i1.x, i1.y};
                    acc = __builtin_amdgcn_mfma_f32_16x16x32_bf16(a0.h, zf[0][Nt].h, acc, 0, 0, 0);
                    acc = __builtin_amdgcn_mfma_f32_16x16x32_bf16(a1.h, zf[1][Nt].h, acc, 0, 0, 0);
                    S[Nt] = acc;   // S = zz + |c|^2 - 2 z.c; row = center 64c+16Mt+4q+r
                }

                const int Kt = Mt >> 1;
                const int qt = (2 * Mt + (q >> 1)) & 3;
                const f32x2 eps2 = (f32x2){EPSF, EPSF};
#pragma unroll
                for (int Nt = 0; Nt < 2; ++Nt) {
                    // packed elementwise: pairs (r0,r1) and (r2,r3)
                    f32x2 s0 = (f32x2){S[Nt][0], S[Nt][1]};
                    f32x2 s1 = (f32x2){S[Nt][2], S[Nt][3]};
                    f32x2 r20 = max2(s0, eps2);                 // == max(.,0)+eps here
                    f32x2 r21 = max2(s1, eps2);
                    f32x2 rin0, rin1;
                    rin0.x = __builtin_amdgcn_rsqf(r20.x);
                    rin0.y = __builtin_amdgcn_rsqf(r20.y);
                    rin1.x = __builtin_amdgcn_rsqf(r21.x);
                    rin1.y = __builtin_amdgcn_rsqf(r21.y);
                    f32x2 mur0 = mulo * rin0, mur1 = muhi * rin1;   // pk_mul
                    nacc2[Nt] += mur0;                              // pk_add
                    nacc2[Nt] += mur1;
                    f32x2 q0 = rin0 * rin0, q1 = rin1 * rin1;       // pk_mul
                    f32x2 wv0 = mur0 * q0,  wv1 = mur1 * q1;        // mu / r^3
                    swp2[Nt] += wv0;
                    swp2[Nt] += wv1;
                    const int pos = ((Kt * 2 + Nt) * 64 + m16 + 16 * qt) * 4 + 2 * (q & 1);
                    *(uint2*)(wp + pos) = make_uint2(bfpt(wv0.x, wv0.y),
                                                     bfpt(wv1.x, wv1.y));
                }
            }

            // G-phase: wf frags (lane-linear LDS) + global ga frags (L2)
            FragU wf[2][2];
#pragma unroll
            for (int Kt = 0; Kt < 2; ++Kt)
#pragma unroll
                for (int Nt = 0; Nt < 2; ++Nt)
                    wf[Kt][Nt].i = sWF[w][Kt * 2 + Nt][lane];
#pragma unroll
            for (int Mt = 0; Mt < 4; ++Mt) {
                FragU ga0, ga1;
                ga0.i = wsG[((Mt * 4 + c) * 2 + 0) * 64 + lane];
                ga1.i = wsG[((Mt * 4 + c) * 2 + 1) * 64 + lane];
#pragma unroll
                for (int Nt = 0; Nt < 2; ++Nt) {
                    g[Mt][Nt] = __builtin_amdgcn_mfma_f32_16x16x32_bf16(ga0.h, wf[0][Nt].h, g[Mt][Nt], 0, 0, 0);
                    g[Mt][Nt] = __builtin_amdgcn_mfma_f32_16x16x32_bf16(ga1.h, wf[1][Nt].h, g[Mt][Nt], 0, 0, 0);
                }
            }
        }

        // reduce n, sw across q groups; packed z update
        float tco[2], swf[2];
#pragma unroll
        for (int Nt = 0; Nt < 2; ++Nt) {
            float a = nacc2[Nt].x + nacc2[Nt].y;
            a += __shfl_xor(a, 16, 64);
            a += __shfl_xor(a, 32, 64);
            float b = swp2[Nt].x + swp2[Nt].y;
            b += __shfl_xor(b, 16, 64);
            b += __shfl_xor(b, 32, 64);
            tco[Nt] = DTB * __builtin_amdgcn_rcpf(1.f + a);
            swf[Nt] = b;
        }
        const f32x2 lo2 = (f32x2){-3.f, -3.f}, hi2 = (f32x2){3.f, 3.f};
#pragma unroll
        for (int Mt = 0; Mt < 4; ++Mt)
#pragma unroll
            for (int Nt = 0; Nt < 2; ++Nt) {
                const f32x2 sw2 = (f32x2){swf[Nt], swf[Nt]};
                const f32x2 tc2 = (f32x2){tco[Nt], tco[Nt]};
#pragma unroll
                for (int p = 0; p < 2; ++p) {
                    f32x2 zp = (f32x2){z[Mt][Nt][2 * p], z[Mt][Nt][2 * p + 1]};
                    f32x2 gp = (f32x2){g[Mt][Nt][2 * p], g[Mt][Nt][2 * p + 1]};
                    f32x2 gd = gp - sw2 * zp;          // pk_fma
                    f32x2 zn = zp + tc2 * gd;          // pk_fma
                    zn = min2(max2(zn, lo2), hi2);     // pk_max + pk_min
                    z[Mt][Nt][2 * p]     = zn.x;
                    z[Mt][Nt][2 * p + 1] = zn.y;
                }
            }
    }

    // direct C/D-layout store (16B segments, rows covered across lanes)
#pragma unroll
    for (int Mt = 0; Mt < 4; ++Mt)
#pragma unroll
        for (int Nt = 0; Nt < 2; ++Nt)
            *(f32x4*)(z_out + (size_t)(pbase + 32 * w + m16 + 16 * Nt) * 64
                      + 16 * Mt + 4 * q) = z[Mt][Nt];
}

extern "C" void kernel_launch(void* const* d_in, const int* in_sizes, int n_in,
                              void* d_out, int out_size, void* d_ws, size_t ws_size,
                              hipStream_t stream) {
    const float* z       = (const float*)d_in[0];
    const float* centers = (const float*)d_in[1];
    const float* mus     = (const float*)d_in[2];
    float* out           = (float*)d_out;
    unsigned* ws         = (unsigned*)d_ws;

    pm_prep<<<dim3(17), dim3(256), 0, stream>>>(centers, mus, ws);
    // 131072 particles / 128 per block (4 waves x 32) = 1024 blocks
    pm_main<<<dim3(1024), dim3(256), 0, stream>>>(z, ws, out);
}